// Round 4
// baseline (76.226 us; speedup 1.0000x reference)
//
#include <hip/hip_runtime.h>
#include <math.h>

#define N_NODES 100000
#define N_EDGES 1600000
#define IN_DIM  128
#define OUT_DIM 32
#define LEAKY   0.2f

typedef unsigned int uint;
typedef unsigned short ushort;

// pack two floats to bf16 pair (round-to-nearest-even)
__device__ __forceinline__ uint bf16pk(float a, float b) {
    uint ua = __float_as_uint(a); ua = (ua + 0x7fffu + ((ua >> 16) & 1u)) >> 16;
    uint ub = __float_as_uint(b); ub = (ub + 0x7fffu + ((ub >> 16) & 1u)) >> 16;
    return ua | (ub << 16);
}
__device__ __forceinline__ float bff(ushort u) {
    return __uint_as_float(((uint)u) << 16);
}

// ---------------- Kernel A: z = X @ W (bf16 out), s_src, s_dst ----------------
// Wave = 16 rows x 4 k-quarter lanes. Each lane holds its 128B row-quarter in
// registers (8 float4 global loads, all hitting one 128B line; wave covers 8KB
// contiguous). W broadcast from LDS: 4 k-quarter sections with section stride
// 1160 dwords (== 8 mod 32 banks) -> the 4 distinct W-row addresses per
// instruction land in 4 disjoint bank groups; 16-lane same-addr = broadcast.
// No mid-kernel barriers, LDS 18.6KB.
__global__ __launch_bounds__(256, 3) void gemm_s_kernel(
    const float* __restrict__ X, const float* __restrict__ W,
    const float* __restrict__ a_src, const float* __restrict__ a_dst,
    uint* __restrict__ z, float* __restrict__ ssrc, float* __restrict__ sdst)
{
    __shared__ float Wl[4 * 1160];     // section q: [kk*36 + c], kk,c in 0..31
    __shared__ float asl[OUT_DIM], adl[OUT_DIM];

    const int t = threadIdx.x;
    for (int i = t; i < IN_DIM * OUT_DIM; i += 256) {
        const int k = i >> 5, c = i & 31;
        Wl[(k >> 5) * 1160 + (k & 31) * 36 + c] = W[i];
    }
    if (t < OUT_DIM) { asl[t] = a_src[t]; adl[t] = a_dst[t]; }
    __syncthreads();

    const int q   = t & 3;
    const int row = blockIdx.x * 64 + (t >> 2);
    const bool live = (row < N_NODES);

    float4 xv[8];
    if (live) {
        const float4* xp = reinterpret_cast<const float4*>(X + (size_t)row * IN_DIM + (q << 5));
        #pragma unroll
        for (int j = 0; j < 8; ++j) xv[j] = xp[j];
    } else {
        #pragma unroll
        for (int j = 0; j < 8; ++j) xv[j] = make_float4(0.f, 0.f, 0.f, 0.f);
    }

    float acc[OUT_DIM];
    #pragma unroll
    for (int c = 0; c < OUT_DIM; ++c) acc[c] = 0.f;

    const float* wq = &Wl[q * 1160];
    #pragma unroll
    for (int j = 0; j < 8; ++j) {
        #pragma unroll
        for (int e = 0; e < 4; ++e) {
            const int kk = (j << 2) + e;
            const float x = (e == 0) ? xv[j].x : (e == 1) ? xv[j].y
                          : (e == 2) ? xv[j].z : xv[j].w;
            #pragma unroll
            for (int c4 = 0; c4 < 8; ++c4) {
                const float4 w = *reinterpret_cast<const float4*>(&wq[kk * 36 + (c4 << 2)]);
                acc[c4 * 4 + 0] = fmaf(x, w.x, acc[c4 * 4 + 0]);
                acc[c4 * 4 + 1] = fmaf(x, w.y, acc[c4 * 4 + 1]);
                acc[c4 * 4 + 2] = fmaf(x, w.z, acc[c4 * 4 + 2]);
                acc[c4 * 4 + 3] = fmaf(x, w.w, acc[c4 * 4 + 3]);
            }
        }
    }

    // reduce across the 4 k-quarter lanes (quad butterfly)
    #pragma unroll
    for (int c = 0; c < OUT_DIM; ++c) {
        acc[c] += __shfl_xor(acc[c], 1, 64);
        acc[c] += __shfl_xor(acc[c], 2, 64);
    }

    if (!live) return;

    float ss = 0.f, dd = 0.f;
    #pragma unroll
    for (int c = 0; c < OUT_DIM; ++c) {
        ss = fmaf(acc[c], asl[c], ss);
        dd = fmaf(acc[c], adl[c], dd);
    }
    if (q == 0) ssrc[row] = ss;
    if (q == 1) sdst[row] = dd;

    // lane q stores channels [8q, 8q+8) as one uint4 of packed bf16
    uint4 pk;
    if (q == 0)
        pk = make_uint4(bf16pk(acc[0],  acc[1]),  bf16pk(acc[2],  acc[3]),
                        bf16pk(acc[4],  acc[5]),  bf16pk(acc[6],  acc[7]));
    else if (q == 1)
        pk = make_uint4(bf16pk(acc[8],  acc[9]),  bf16pk(acc[10], acc[11]),
                        bf16pk(acc[12], acc[13]), bf16pk(acc[14], acc[15]));
    else if (q == 2)
        pk = make_uint4(bf16pk(acc[16], acc[17]), bf16pk(acc[18], acc[19]),
                        bf16pk(acc[20], acc[21]), bf16pk(acc[22], acc[23]));
    else
        pk = make_uint4(bf16pk(acc[24], acc[25]), bf16pk(acc[26], acc[27]),
                        bf16pk(acc[28], acc[29]), bf16pk(acc[30], acc[31]));
    reinterpret_cast<uint4*>(z)[row * 4 + q] = pk;
}

// ---------------- Kernel B: CSR offsets from sorted dst ----------------
__global__ __launch_bounds__(256) void offsets_kernel(
    const int* __restrict__ dst, int* __restrict__ off)
{
    const int e = blockIdx.x * blockDim.x + threadIdx.x;
    if (e >= N_EDGES) return;
    const int d = dst[e];
    const int dprev = (e == 0) ? -1 : dst[e - 1];
    for (int n = dprev + 1; n <= d; ++n) off[n] = e;
    if (e == N_EDGES - 1) {
        for (int n = d + 1; n <= N_NODES; ++n) off[n] = N_EDGES;
    }
}

// ---------------- Kernel C: fused softmax + aggregation ----------------
// One 32-lane group per dst node, lane = channel. 32-edge chunks: coalesced
// src load + lane-parallel exp; (s*32, v) staged in parity-double-buffered
// LDS; gather loop 16-deep (16 independent bf16 z loads in flight, 4 accs).
__global__ __launch_bounds__(256) void agg_kernel(
    const ushort* __restrict__ z, const float* __restrict__ ssrc,
    const float* __restrict__ sdst, const int* __restrict__ src,
    const int* __restrict__ off, float* __restrict__ out)
{
    __shared__ float2 sv[8][2][32];
    const int t = threadIdx.x;
    const int g = t >> 5, c = t & 31;
    const int n = blockIdx.x * 8 + g;
    if (n >= N_NODES) return;

    const int lo = off[n], hi = off[n + 1];
    const float sd = sdst[n];

    float a0 = 0.f, a1 = 0.f, a2 = 0.f, a3 = 0.f, den = 0.f;
    int par = 0;

    for (int base = lo; base < hi; base += 32, par ^= 1) {
        int srow = 0; float v = 0.f;
        const int e = base + c;
        if (e < hi) {
            const int s = src[e];
            srow = s << 5;
            float x = ssrc[s] + sd;
            x = (x > 0.f) ? x : LEAKY * x;
            v = __expf(x);
        }
        den += v;
        sv[g][par][c] = make_float2(__int_as_float(srow), v);
        const int cnt = min(32, hi - base);
        int j = 0;
        for (; j + 16 <= cnt; j += 16) {
            const float4 q0 = *reinterpret_cast<const float4*>(&sv[g][par][j + 0]);
            const float4 q1 = *reinterpret_cast<const float4*>(&sv[g][par][j + 2]);
            const float4 q2 = *reinterpret_cast<const float4*>(&sv[g][par][j + 4]);
            const float4 q3 = *reinterpret_cast<const float4*>(&sv[g][par][j + 6]);
            const float4 q4 = *reinterpret_cast<const float4*>(&sv[g][par][j + 8]);
            const float4 q5 = *reinterpret_cast<const float4*>(&sv[g][par][j + 10]);
            const float4 q6 = *reinterpret_cast<const float4*>(&sv[g][par][j + 12]);
            const float4 q7 = *reinterpret_cast<const float4*>(&sv[g][par][j + 14]);
            const float z0  = bff(z[__float_as_int(q0.x) + c]);
            const float z1  = bff(z[__float_as_int(q0.z) + c]);
            const float z2  = bff(z[__float_as_int(q1.x) + c]);
            const float z3  = bff(z[__float_as_int(q1.z) + c]);
            const float z4  = bff(z[__float_as_int(q2.x) + c]);
            const float z5  = bff(z[__float_as_int(q2.z) + c]);
            const float z6  = bff(z[__float_as_int(q3.x) + c]);
            const float z7  = bff(z[__float_as_int(q3.z) + c]);
            const float z8  = bff(z[__float_as_int(q4.x) + c]);
            const float z9  = bff(z[__float_as_int(q4.z) + c]);
            const float z10 = bff(z[__float_as_int(q5.x) + c]);
            const float z11 = bff(z[__float_as_int(q5.z) + c]);
            const float z12 = bff(z[__float_as_int(q6.x) + c]);
            const float z13 = bff(z[__float_as_int(q6.z) + c]);
            const float z14 = bff(z[__float_as_int(q7.x) + c]);
            const float z15 = bff(z[__float_as_int(q7.z) + c]);
            a0 = fmaf(q0.y, z0,  a0); a1 = fmaf(q0.w, z1,  a1);
            a2 = fmaf(q1.y, z2,  a2); a3 = fmaf(q1.w, z3,  a3);
            a0 = fmaf(q2.y, z4,  a0); a1 = fmaf(q2.w, z5,  a1);
            a2 = fmaf(q3.y, z6,  a2); a3 = fmaf(q3.w, z7,  a3);
            a0 = fmaf(q4.y, z8,  a0); a1 = fmaf(q4.w, z9,  a1);
            a2 = fmaf(q5.y, z10, a2); a3 = fmaf(q5.w, z11, a3);
            a0 = fmaf(q6.y, z12, a0); a1 = fmaf(q6.w, z13, a1);
            a2 = fmaf(q7.y, z14, a2); a3 = fmaf(q7.w, z15, a3);
        }
        for (; j + 4 <= cnt; j += 4) {
            const float4 q0 = *reinterpret_cast<const float4*>(&sv[g][par][j + 0]);
            const float4 q1 = *reinterpret_cast<const float4*>(&sv[g][par][j + 2]);
            const float z0 = bff(z[__float_as_int(q0.x) + c]);
            const float z1 = bff(z[__float_as_int(q0.z) + c]);
            const float z2 = bff(z[__float_as_int(q1.x) + c]);
            const float z3 = bff(z[__float_as_int(q1.z) + c]);
            a0 = fmaf(q0.y, z0, a0); a1 = fmaf(q0.w, z1, a1);
            a2 = fmaf(q1.y, z2, a2); a3 = fmaf(q1.w, z3, a3);
        }
        for (; j < cnt; ++j) {
            const float2 p = sv[g][par][j];
            a0 = fmaf(p.y, bff(z[__float_as_int(p.x) + c]), a0);
        }
    }

    float acc = (a0 + a1) + (a2 + a3);
    #pragma unroll
    for (int m = 16; m >= 1; m >>= 1) den += __shfl_xor(den, m, 64);

    const float r = (den > 0.f) ? (acc / den) : 0.f;
    out[n * OUT_DIM + c] = fmaxf(r, 0.f);
}

// ---------------- launch ----------------
extern "C" void kernel_launch(void* const* d_in, const int* in_sizes, int n_in,
                              void* d_out, int out_size, void* d_ws, size_t ws_size,
                              hipStream_t stream) {
    const float* X     = (const float*)d_in[0];
    const float* W     = (const float*)d_in[1];
    const float* a_src = (const float*)d_in[2];
    const float* a_dst = (const float*)d_in[3];
    const int*   src   = (const int*)d_in[4];
    const int*   dst   = (const int*)d_in[5];
    float* out = (float*)d_out;

    char* ws = (char*)d_ws;
    uint*  z    = (uint*)ws;    ws += (size_t)N_NODES * OUT_DIM * sizeof(ushort);  // bf16
    float* ssrc = (float*)ws;   ws += (size_t)N_NODES * sizeof(float);
    float* sdst = (float*)ws;   ws += (size_t)N_NODES * sizeof(float);
    int*   off  = (int*)ws;     ws += (size_t)(N_NODES + 1) * sizeof(int);

    offsets_kernel<<<(N_EDGES + 255) / 256, 256, 0, stream>>>(dst, off);
    gemm_s_kernel<<<(N_NODES + 63) / 64, 256, 0, stream>>>(X, W, a_src, a_dst, z, ssrc, sdst);
    agg_kernel<<<(N_NODES + 7) / 8, 256, 0, stream>>>((const ushort*)z, ssrc, sdst, src, off, out);
}